// Round 1
// baseline (241.147 us; speedup 1.0000x reference)
//
#include <hip/hip_runtime.h>
#include <math.h>

// Problem constants (B=16, C=3, H=256, W=256, P=64)
#define HW      65536
#define NPROJ   64
#define NBC     48            // B*C
#define NROWS   (NBC * NPROJ) // 3072 theta rows

// Kernel 1: one block per theta row r = bc*64 + p.
// Computes dot(f1,theta_r), dot(f2,theta_r), dot(theta_r,theta_r) in one pass,
// writes normalized projections p1[r], p2[r].
__global__ __launch_bounds__(256) void swd_proj_kernel(
    const float* __restrict__ f1,
    const float* __restrict__ f2,
    const float* __restrict__ theta,
    float* __restrict__ p1out,
    float* __restrict__ p2out)
{
    const int r  = blockIdx.x;   // 0..3071
    const int bc = r >> 6;       // r / 64
    const float4* __restrict__ t4 = (const float4*)(theta + (size_t)r  * HW);
    const float4* __restrict__ a4 = (const float4*)(f1    + (size_t)bc * HW);
    const float4* __restrict__ b4 = (const float4*)(f2    + (size_t)bc * HW);

    float s1 = 0.f, s2 = 0.f, sn = 0.f;
    const int tid = threadIdx.x;

    // 65536/4 = 16384 float4 per row; 16384/256 = 64 iters/thread
    #pragma unroll 4
    for (int i = tid; i < HW / 4; i += 256) {
        float4 t = t4[i];
        float4 a = a4[i];
        float4 b = b4[i];
        s1 += t.x * a.x + t.y * a.y + t.z * a.z + t.w * a.w;
        s2 += t.x * b.x + t.y * b.y + t.z * b.z + t.w * b.w;
        sn += t.x * t.x + t.y * t.y + t.z * t.z + t.w * t.w;
    }

    // wave (64-lane) butterfly reduce
    for (int j = 32; j > 0; j >>= 1) {
        s1 += __shfl_xor(s1, j);
        s2 += __shfl_xor(s2, j);
        sn += __shfl_xor(sn, j);
    }

    __shared__ float red[4][3];
    const int wave = tid >> 6;
    if ((tid & 63) == 0) {
        red[wave][0] = s1;
        red[wave][1] = s2;
        red[wave][2] = sn;
    }
    __syncthreads();
    if (tid == 0) {
        float t1 = red[0][0] + red[1][0] + red[2][0] + red[3][0];
        float t2 = red[0][1] + red[1][1] + red[2][1] + red[3][1];
        float tn = red[0][2] + red[1][2] + red[2][2] + red[3][2];
        float inv = 1.0f / sqrtf(tn);
        p1out[r] = t1 * inv;
        p2out[r] = t2 * inv;
    }
}

// Kernel 2: single block, 16 waves. Each wave handles bc = wave, wave+16, wave+32.
// 64-lane in-register bitonic sort (P == wavefront size), squared-diff reduce,
// sqrt, then mean over the 48 (b,c) pairs.
__global__ __launch_bounds__(1024) void swd_sort_kernel(
    const float* __restrict__ p1,
    const float* __restrict__ p2,
    float* __restrict__ out)
{
    const int tid  = threadIdx.x;
    const int lane = tid & 63;
    const int wave = tid >> 6;   // 0..15

    float acc = 0.f;
    for (int bc = wave; bc < NBC; bc += 16) {
        float v1 = p1[bc * NPROJ + lane];
        float v2 = p2[bc * NPROJ + lane];

        // bitonic sort ascending across the 64 lanes
        #pragma unroll
        for (int k = 2; k <= 64; k <<= 1) {
            #pragma unroll
            for (int j = k >> 1; j > 0; j >>= 1) {
                float o1 = __shfl_xor(v1, j);
                float o2 = __shfl_xor(v2, j);
                bool up      = ((lane & k) == 0);
                bool lower   = ((lane & j) == 0);
                bool keepMin = (lower == up);
                v1 = keepMin ? fminf(v1, o1) : fmaxf(v1, o1);
                v2 = keepMin ? fminf(v2, o2) : fmaxf(v2, o2);
            }
        }

        float d = v1 - v2;
        float s = d * d;
        for (int j = 32; j > 0; j >>= 1) s += __shfl_xor(s, j);
        if (lane == 0) acc += sqrtf(s);
    }

    __shared__ float red[16];
    if (lane == 0) red[wave] = acc;
    __syncthreads();
    if (tid == 0) {
        float s = 0.f;
        #pragma unroll
        for (int i = 0; i < 16; ++i) s += red[i];
        out[0] = s * (1.0f / NBC);
    }
}

extern "C" void kernel_launch(void* const* d_in, const int* in_sizes, int n_in,
                              void* d_out, int out_size, void* d_ws, size_t ws_size,
                              hipStream_t stream) {
    const float* f1    = (const float*)d_in[0];  // batch1 [16,3,256,256]
    const float* f2    = (const float*)d_in[1];  // batch2 [16,3,256,256]
    const float* theta = (const float*)d_in[2];  // theta  [16,3,64,65536]
    float* out = (float*)d_out;

    float* p1 = (float*)d_ws;        // NROWS floats
    float* p2 = p1 + NROWS;          // NROWS floats (24 KB total)

    swd_proj_kernel<<<NROWS, 256, 0, stream>>>(f1, f2, theta, p1, p2);
    swd_sort_kernel<<<1, 1024, 0, stream>>>(p1, p2, out);
}

// Round 2
// 190.369 us; speedup vs baseline: 1.2667x; 1.2667x over previous
//
#include <hip/hip_runtime.h>
#include <math.h>

// Problem constants (B=16, C=3, H=256, W=256, P=64)
#define HW      65536
#define NPROJ   64
#define NBC     48            // B*C
#define NROWS   (NBC * NPROJ) // 3072 theta rows

typedef float f32x4 __attribute__((ext_vector_type(4)));

// Kernel 1: one block per theta row r = bc*64 + p.
// Computes dot(f1,theta_r), dot(f2,theta_r), dot(theta_r,theta_r) in one pass,
// writes normalized projections p1[r], p2[r].
// theta is read with NONTEMPORAL loads (zero reuse -> don't evict f1/f2 from L2/L3).
__global__ __launch_bounds__(256) void swd_proj_kernel(
    const float* __restrict__ f1,
    const float* __restrict__ f2,
    const float* __restrict__ theta,
    float* __restrict__ p1out,
    float* __restrict__ p2out)
{
    const int r  = blockIdx.x;   // 0..3071
    const int bc = r >> 6;       // r / 64
    const f32x4* __restrict__ t4 = (const f32x4*)(theta + (size_t)r  * HW);
    const f32x4* __restrict__ a4 = (const f32x4*)(f1    + (size_t)bc * HW);
    const f32x4* __restrict__ b4 = (const f32x4*)(f2    + (size_t)bc * HW);

    float s1 = 0.f, s2 = 0.f, sn = 0.f;
    const int tid = threadIdx.x;

    // 65536/4 = 16384 float4 per row; 16384/256 = 64 iters/thread
    #pragma unroll 4
    for (int i = tid; i < HW / 4; i += 256) {
        f32x4 t = __builtin_nontemporal_load(t4 + i);  // streaming: nt flag
        f32x4 a = a4[i];                               // cached: reused by 64 blocks
        f32x4 b = b4[i];
        s1 += t.x * a.x + t.y * a.y + t.z * a.z + t.w * a.w;
        s2 += t.x * b.x + t.y * b.y + t.z * b.z + t.w * b.w;
        sn += t.x * t.x + t.y * t.y + t.z * t.z + t.w * t.w;
    }

    // wave (64-lane) butterfly reduce
    for (int j = 32; j > 0; j >>= 1) {
        s1 += __shfl_xor(s1, j);
        s2 += __shfl_xor(s2, j);
        sn += __shfl_xor(sn, j);
    }

    __shared__ float red[4][3];
    const int wave = tid >> 6;
    if ((tid & 63) == 0) {
        red[wave][0] = s1;
        red[wave][1] = s2;
        red[wave][2] = sn;
    }
    __syncthreads();
    if (tid == 0) {
        float t1 = red[0][0] + red[1][0] + red[2][0] + red[3][0];
        float t2 = red[0][1] + red[1][1] + red[2][1] + red[3][1];
        float tn = red[0][2] + red[1][2] + red[2][2] + red[3][2];
        float inv = 1.0f / sqrtf(tn);
        p1out[r] = t1 * inv;
        p2out[r] = t2 * inv;
    }
}

// Kernel 2: single block, 16 waves. Each wave handles bc = wave, wave+16, wave+32.
// 64-lane in-register bitonic sort (P == wavefront size), squared-diff reduce,
// sqrt, then mean over the 48 (b,c) pairs.
__global__ __launch_bounds__(1024) void swd_sort_kernel(
    const float* __restrict__ p1,
    const float* __restrict__ p2,
    float* __restrict__ out)
{
    const int tid  = threadIdx.x;
    const int lane = tid & 63;
    const int wave = tid >> 6;   // 0..15

    float acc = 0.f;
    for (int bc = wave; bc < NBC; bc += 16) {
        float v1 = p1[bc * NPROJ + lane];
        float v2 = p2[bc * NPROJ + lane];

        // bitonic sort ascending across the 64 lanes
        #pragma unroll
        for (int k = 2; k <= 64; k <<= 1) {
            #pragma unroll
            for (int j = k >> 1; j > 0; j >>= 1) {
                float o1 = __shfl_xor(v1, j);
                float o2 = __shfl_xor(v2, j);
                bool up      = ((lane & k) == 0);
                bool lower   = ((lane & j) == 0);
                bool keepMin = (lower == up);
                v1 = keepMin ? fminf(v1, o1) : fmaxf(v1, o1);
                v2 = keepMin ? fminf(v2, o2) : fmaxf(v2, o2);
            }
        }

        float d = v1 - v2;
        float s = d * d;
        for (int j = 32; j > 0; j >>= 1) s += __shfl_xor(s, j);
        if (lane == 0) acc += sqrtf(s);
    }

    __shared__ float red[16];
    if (lane == 0) red[wave] = acc;
    __syncthreads();
    if (tid == 0) {
        float s = 0.f;
        #pragma unroll
        for (int i = 0; i < 16; ++i) s += red[i];
        out[0] = s * (1.0f / NBC);
    }
}

extern "C" void kernel_launch(void* const* d_in, const int* in_sizes, int n_in,
                              void* d_out, int out_size, void* d_ws, size_t ws_size,
                              hipStream_t stream) {
    const float* f1    = (const float*)d_in[0];  // batch1 [16,3,256,256]
    const float* f2    = (const float*)d_in[1];  // batch2 [16,3,256,256]
    const float* theta = (const float*)d_in[2];  // theta  [16,3,64,65536]
    float* out = (float*)d_out;

    float* p1 = (float*)d_ws;        // NROWS floats
    float* p2 = p1 + NROWS;          // NROWS floats (24 KB total)

    swd_proj_kernel<<<NROWS, 256, 0, stream>>>(f1, f2, theta, p1, p2);
    swd_sort_kernel<<<1, 1024, 0, stream>>>(p1, p2, out);
}

// Round 3
// 135.732 us; speedup vs baseline: 1.7766x; 1.4025x over previous
//
#include <hip/hip_runtime.h>
#include <math.h>

// Problem constants (B=16, C=3, H=256, W=256, P=64)
#define HW      65536
#define NPROJ   64
#define NBC     48            // B*C
#define NROWS   (NBC * NPROJ) // 3072 theta rows
#define RPB     4             // theta rows per block
#define NBLK    (NROWS / RPB) // 768 blocks; 768 % 8 == 0 -> clean XCD swizzle
#define BPX     (NBLK / 8)    // 96 blocks per XCD

typedef float f32x4 __attribute__((ext_vector_type(4)));

// Kernel 1: one block per 4 theta rows (same bc).
// XCD-swizzled so all 16 blocks of a bc land on ONE XCD -> f1/f2 rows are
// HBM-fetched once and stay L2-resident. theta is nontemporal (zero reuse).
// Computes dot(f1,theta_r), dot(f2,theta_r), dot(theta_r,theta_r) in one pass,
// writes normalized projections p1[r], p2[r].
__global__ __launch_bounds__(256) void swd_proj_kernel(
    const float* __restrict__ f1,
    const float* __restrict__ f2,
    const float* __restrict__ theta,
    float* __restrict__ p1out,
    float* __restrict__ p2out)
{
    // bijective XCD swizzle: dispatch round-robins blockIdx%8 across XCDs;
    // remap so each XCD owns a contiguous range of row-groups (same-bc together).
    const int orig = blockIdx.x;                 // 0..767
    const int swz  = (orig & 7) * BPX + (orig >> 3);
    const int bc   = swz >> 4;                   // 16 groups per bc
    const int r0   = swz << 2;                   // first of 4 theta rows

    const f32x4* __restrict__ a4 = (const f32x4*)(f1 + (size_t)bc * HW);
    const f32x4* __restrict__ b4 = (const f32x4*)(f2 + (size_t)bc * HW);
    const f32x4* __restrict__ tp0 = (const f32x4*)(theta + (size_t)(r0 + 0) * HW);
    const f32x4* __restrict__ tp1 = (const f32x4*)(theta + (size_t)(r0 + 1) * HW);
    const f32x4* __restrict__ tp2 = (const f32x4*)(theta + (size_t)(r0 + 2) * HW);
    const f32x4* __restrict__ tp3 = (const f32x4*)(theta + (size_t)(r0 + 3) * HW);

    float s1[RPB] = {0.f, 0.f, 0.f, 0.f};
    float s2[RPB] = {0.f, 0.f, 0.f, 0.f};
    float sn[RPB] = {0.f, 0.f, 0.f, 0.f};
    const int tid = threadIdx.x;

    #pragma unroll 2
    for (int i = tid; i < HW / 4; i += 256) {
        f32x4 a = a4[i];
        f32x4 b = b4[i];
        f32x4 t0 = __builtin_nontemporal_load(tp0 + i);
        f32x4 t1 = __builtin_nontemporal_load(tp1 + i);
        f32x4 t2 = __builtin_nontemporal_load(tp2 + i);
        f32x4 t3 = __builtin_nontemporal_load(tp3 + i);

        s1[0] += t0.x*a.x + t0.y*a.y + t0.z*a.z + t0.w*a.w;
        s2[0] += t0.x*b.x + t0.y*b.y + t0.z*b.z + t0.w*b.w;
        sn[0] += t0.x*t0.x + t0.y*t0.y + t0.z*t0.z + t0.w*t0.w;

        s1[1] += t1.x*a.x + t1.y*a.y + t1.z*a.z + t1.w*a.w;
        s2[1] += t1.x*b.x + t1.y*b.y + t1.z*b.z + t1.w*b.w;
        sn[1] += t1.x*t1.x + t1.y*t1.y + t1.z*t1.z + t1.w*t1.w;

        s1[2] += t2.x*a.x + t2.y*a.y + t2.z*a.z + t2.w*a.w;
        s2[2] += t2.x*b.x + t2.y*b.y + t2.z*b.z + t2.w*b.w;
        sn[2] += t2.x*t2.x + t2.y*t2.y + t2.z*t2.z + t2.w*t2.w;

        s1[3] += t3.x*a.x + t3.y*a.y + t3.z*a.z + t3.w*a.w;
        s2[3] += t3.x*b.x + t3.y*b.y + t3.z*b.z + t3.w*b.w;
        sn[3] += t3.x*t3.x + t3.y*t3.y + t3.z*t3.z + t3.w*t3.w;
    }

    // wave (64-lane) butterfly reduce, then LDS across the 4 waves
    #pragma unroll
    for (int j = 32; j > 0; j >>= 1) {
        #pragma unroll
        for (int p = 0; p < RPB; ++p) {
            s1[p] += __shfl_xor(s1[p], j);
            s2[p] += __shfl_xor(s2[p], j);
            sn[p] += __shfl_xor(sn[p], j);
        }
    }

    __shared__ float red[4][RPB][3];
    const int wave = tid >> 6;
    if ((tid & 63) == 0) {
        #pragma unroll
        for (int p = 0; p < RPB; ++p) {
            red[wave][p][0] = s1[p];
            red[wave][p][1] = s2[p];
            red[wave][p][2] = sn[p];
        }
    }
    __syncthreads();
    if (tid < RPB) {
        const int p = tid;
        float t1 = red[0][p][0] + red[1][p][0] + red[2][p][0] + red[3][p][0];
        float t2 = red[0][p][1] + red[1][p][1] + red[2][p][1] + red[3][p][1];
        float tn = red[0][p][2] + red[1][p][2] + red[2][p][2] + red[3][p][2];
        float inv = 1.0f / sqrtf(tn);
        p1out[r0 + p] = t1 * inv;
        p2out[r0 + p] = t2 * inv;
    }
}

// Kernel 2: single block, 16 waves. Each wave handles bc = wave, wave+16, wave+32.
// 64-lane in-register bitonic sort (P == wavefront size), squared-diff reduce,
// sqrt, then mean over the 48 (b,c) pairs.
__global__ __launch_bounds__(1024) void swd_sort_kernel(
    const float* __restrict__ p1,
    const float* __restrict__ p2,
    float* __restrict__ out)
{
    const int tid  = threadIdx.x;
    const int lane = tid & 63;
    const int wave = tid >> 6;   // 0..15

    float acc = 0.f;
    for (int bc = wave; bc < NBC; bc += 16) {
        float v1 = p1[bc * NPROJ + lane];
        float v2 = p2[bc * NPROJ + lane];

        // bitonic sort ascending across the 64 lanes
        #pragma unroll
        for (int k = 2; k <= 64; k <<= 1) {
            #pragma unroll
            for (int j = k >> 1; j > 0; j >>= 1) {
                float o1 = __shfl_xor(v1, j);
                float o2 = __shfl_xor(v2, j);
                bool up      = ((lane & k) == 0);
                bool lower   = ((lane & j) == 0);
                bool keepMin = (lower == up);
                v1 = keepMin ? fminf(v1, o1) : fmaxf(v1, o1);
                v2 = keepMin ? fminf(v2, o2) : fmaxf(v2, o2);
            }
        }

        float d = v1 - v2;
        float s = d * d;
        for (int j = 32; j > 0; j >>= 1) s += __shfl_xor(s, j);
        if (lane == 0) acc += sqrtf(s);
    }

    __shared__ float red[16];
    if (lane == 0) red[wave] = acc;
    __syncthreads();
    if (tid == 0) {
        float s = 0.f;
        #pragma unroll
        for (int i = 0; i < 16; ++i) s += red[i];
        out[0] = s * (1.0f / NBC);
    }
}

extern "C" void kernel_launch(void* const* d_in, const int* in_sizes, int n_in,
                              void* d_out, int out_size, void* d_ws, size_t ws_size,
                              hipStream_t stream) {
    const float* f1    = (const float*)d_in[0];  // batch1 [16,3,256,256]
    const float* f2    = (const float*)d_in[1];  // batch2 [16,3,256,256]
    const float* theta = (const float*)d_in[2];  // theta  [16,3,64,65536]
    float* out = (float*)d_out;

    float* p1 = (float*)d_ws;        // NROWS floats
    float* p2 = p1 + NROWS;          // NROWS floats (24 KB total)

    swd_proj_kernel<<<NBLK, 256, 0, stream>>>(f1, f2, theta, p1, p2);
    swd_sort_kernel<<<1, 1024, 0, stream>>>(p1, p2, out);
}